// Round 1
// baseline (3598.997 us; speedup 1.0000x reference)
//
#include <hip/hip_runtime.h>
#include <cstdint>
#include <cstddef>

#define BATCH   512
#define HIDDEN  512
#define EMB     512
#define VOCAB   4096
#define NOBJ    3
#define FEATIN  2048
#define FEATSZ  512
#define MAXLEN  40
#define TSTEPS  38
#define SOS     1
#define EOS     2

// GEMM tile config: C[M,N] = A[M,K] @ B[N,K]^T, 64x64 tile, BK=16, 256 thr, 4x4/thread
#define BM 64
#define BN 64
#define BK 16

static __device__ __forceinline__ unsigned long long pack_key(float v, int col) {
    uint32_t u = __float_as_uint(v);
    u = (u & 0x80000000u) ? ~u : (u | 0x80000000u);   // order-preserving map
    // lower col wins ties: bigger (VOCAB-1-col) wins under max
    return ((unsigned long long)u << 32) | (uint32_t)(VOCAB - 1 - col);
}

// ---------------- feature embed: fe[1536,512] = feats[1536,2048] @ featW[512,2048]^T + featb
__global__ __launch_bounds__(256) void k_fe(const float* __restrict__ feats,
                                            const float* __restrict__ featW,
                                            const float* __restrict__ featb,
                                            float* __restrict__ fe) {
    __shared__ float As[BK][BM];
    __shared__ float Bs[BK][BN];
    const int tid = threadIdx.x;
    const int m0 = blockIdx.y * BM, n0 = blockIdx.x * BN;
    const int tx = tid & 15, ty = tid >> 4;
    const int lrow = tid >> 2, lk = (tid & 3) << 2;
    float acc[4][4] = {};
    for (int k0 = 0; k0 < FEATIN; k0 += BK) {
        float4 a = *(const float4*)&feats[(size_t)(m0 + lrow) * FEATIN + k0 + lk];
        float4 b = *(const float4*)&featW[(size_t)(n0 + lrow) * FEATIN + k0 + lk];
        __syncthreads();
        As[lk+0][lrow] = a.x; As[lk+1][lrow] = a.y; As[lk+2][lrow] = a.z; As[lk+3][lrow] = a.w;
        Bs[lk+0][lrow] = b.x; Bs[lk+1][lrow] = b.y; Bs[lk+2][lrow] = b.z; Bs[lk+3][lrow] = b.w;
        __syncthreads();
#pragma unroll
        for (int kk = 0; kk < BK; ++kk) {
            float4 av = *(const float4*)&As[kk][ty * 4];
            float4 bv = *(const float4*)&Bs[kk][tx * 4];
            float ar[4] = {av.x, av.y, av.z, av.w};
            float br[4] = {bv.x, bv.y, bv.z, bv.w};
#pragma unroll
            for (int i = 0; i < 4; ++i)
#pragma unroll
                for (int j = 0; j < 4; ++j) acc[i][j] += ar[i] * br[j];
        }
    }
#pragma unroll
    for (int i = 0; i < 4; ++i) {
        int r = m0 + ty * 4 + i;
#pragma unroll
        for (int j = 0; j < 4; ++j) {
            int c = n0 + tx * 4 + j;
            fe[(size_t)r * FEATSZ + c] = acc[i][j] + featb[c];
        }
    }
}

// ---------------- h0[512,512] = ft[512,1539] @ initW[512,1539]^T + initb
// ft = [fe(b,o,:) | onehot(target)]; contraction over the 3*512 fe part as GEMM,
// one-hot term added in epilogue. B col remap: ka in [0,1536) -> ka + ka/512.
__global__ __launch_bounds__(256) void k_h0(const float* __restrict__ fe,
                                            const float* __restrict__ initW,
                                            const float* __restrict__ initb,
                                            const int* __restrict__ targets,
                                            float* __restrict__ h) {
    __shared__ float As[BK][BM];
    __shared__ float Bs[BK][BN];
    const int tid = threadIdx.x;
    const int m0 = blockIdx.y * BM, n0 = blockIdx.x * BN;
    const int tx = tid & 15, ty = tid >> 4;
    const int lrow = tid >> 2, lk = (tid & 3) << 2;
    float acc[4][4] = {};
    const int K = NOBJ * FEATSZ;  // 1536
    for (int k0 = 0; k0 < K; k0 += BK) {
        float4 a = *(const float4*)&fe[(size_t)(m0 + lrow) * K + k0 + lk];
        float breg[4];
#pragma unroll
        for (int i = 0; i < 4; ++i) {
            int ka = k0 + lk + i;
            breg[i] = initW[(size_t)(n0 + lrow) * 1539 + ka + (ka >> 9)];
        }
        __syncthreads();
        As[lk+0][lrow] = a.x; As[lk+1][lrow] = a.y; As[lk+2][lrow] = a.z; As[lk+3][lrow] = a.w;
#pragma unroll
        for (int i = 0; i < 4; ++i) Bs[lk + i][lrow] = breg[i];
        __syncthreads();
#pragma unroll
        for (int kk = 0; kk < BK; ++kk) {
            float4 av = *(const float4*)&As[kk][ty * 4];
            float4 bv = *(const float4*)&Bs[kk][tx * 4];
            float ar[4] = {av.x, av.y, av.z, av.w};
            float br[4] = {bv.x, bv.y, bv.z, bv.w};
#pragma unroll
            for (int i = 0; i < 4; ++i)
#pragma unroll
                for (int j = 0; j < 4; ++j) acc[i][j] += ar[i] * br[j];
        }
    }
#pragma unroll
    for (int i = 0; i < 4; ++i) {
        int r = m0 + ty * 4 + i;
        int tg = targets[r];
#pragma unroll
        for (int j = 0; j < 4; ++j) {
            int c = n0 + tx * 4 + j;
            h[(size_t)r * HIDDEN + c] =
                acc[i][j] + initb[c] + initW[(size_t)c * 1539 + tg * 513 + 512];
        }
    }
}

// ---------------- gates: G[512,3072]: cols [0,1536) = x@Wih^T + bih (x = emb_W[pred]),
// cols [1536,3072) = h@Whh^T + bhh
__global__ __launch_bounds__(256) void k_gates(const float* __restrict__ embW,
                                               const float* __restrict__ h,
                                               const float* __restrict__ Wih,
                                               const float* __restrict__ Whh,
                                               const float* __restrict__ bih,
                                               const float* __restrict__ bhh,
                                               const unsigned long long* __restrict__ keys_prev,
                                               float* __restrict__ G) {
    __shared__ float As[BK][BM];
    __shared__ float Bs[BK][BN];
    const int tid = threadIdx.x;
    const int m0 = blockIdx.y * BM;
    const int n0g = blockIdx.x * BN;          // 0..3071
    const bool hhalf = (n0g >= 3 * HIDDEN);   // h-half?
    const int tx = tid & 15, ty = tid >> 4;
    const int lrow = tid >> 2, lk = (tid & 3) << 2;

    const float* Arow;
    if (!hhalf) {
        int tok = SOS;
        if (keys_prev)
            tok = (VOCAB - 1) - (int)(uint32_t)(keys_prev[m0 + lrow] & 0xffffffffULL);
        Arow = embW + (size_t)tok * EMB;
    } else {
        Arow = h + (size_t)(m0 + lrow) * HIDDEN;
    }
    const float* Brow = hhalf ? (Whh + (size_t)(n0g - 3 * HIDDEN + lrow) * HIDDEN)
                              : (Wih + (size_t)(n0g + lrow) * EMB);
    float acc[4][4] = {};
    for (int k0 = 0; k0 < HIDDEN; k0 += BK) {
        float4 a = *(const float4*)&Arow[k0 + lk];
        float4 b = *(const float4*)&Brow[k0 + lk];
        __syncthreads();
        As[lk+0][lrow] = a.x; As[lk+1][lrow] = a.y; As[lk+2][lrow] = a.z; As[lk+3][lrow] = a.w;
        Bs[lk+0][lrow] = b.x; Bs[lk+1][lrow] = b.y; Bs[lk+2][lrow] = b.z; Bs[lk+3][lrow] = b.w;
        __syncthreads();
#pragma unroll
        for (int kk = 0; kk < BK; ++kk) {
            float4 av = *(const float4*)&As[kk][ty * 4];
            float4 bv = *(const float4*)&Bs[kk][tx * 4];
            float ar[4] = {av.x, av.y, av.z, av.w};
            float br[4] = {bv.x, bv.y, bv.z, bv.w};
#pragma unroll
            for (int i = 0; i < 4; ++i)
#pragma unroll
                for (int j = 0; j < 4; ++j) acc[i][j] += ar[i] * br[j];
        }
    }
#pragma unroll
    for (int i = 0; i < 4; ++i) {
        int r = m0 + ty * 4 + i;
#pragma unroll
        for (int j = 0; j < 4; ++j) {
            int cg = n0g + tx * 4 + j;
            int nn = hhalf ? (cg - 3 * HIDDEN) : cg;
            float bias = hhalf ? bhh[nn] : bih[nn];
            G[(size_t)r * (6 * HIDDEN) + cg] = acc[i][j] + bias;
        }
    }
}

// ---------------- GRU elementwise: h = (1-z)*n + z*h
__global__ __launch_bounds__(256) void k_gru(const float* __restrict__ G,
                                             float* __restrict__ h) {
    int idx = blockIdx.x * 256 + threadIdx.x;   // 0..BATCH*HIDDEN-1
    int b = idx >> 9, j = idx & (HIDDEN - 1);
    const float* g = G + (size_t)b * (6 * HIDDEN);
    float ir = g[j], iz = g[j + HIDDEN], inn = g[j + 2 * HIDDEN];
    float hr = g[j + 3 * HIDDEN], hz = g[j + 4 * HIDDEN], hn = g[j + 5 * HIDDEN];
    float r = 1.0f / (1.0f + expf(-(ir + hr)));
    float z = 1.0f / (1.0f + expf(-(iz + hz)));
    float n = tanhf(inn + r * hn);
    float ho = h[idx];
    h[idx] = (1.0f - z) * n + z * ho;
}

// ---------------- logits + argmax: per-row key = max over V of pack(logit+gumbel)
__global__ __launch_bounds__(256) void k_logits(const float* __restrict__ h,
                                                const float* __restrict__ outW,
                                                const float* __restrict__ outb,
                                                const float* __restrict__ gum_t,
                                                unsigned long long* __restrict__ keys_t) {
    __shared__ float As[BK][BM];
    __shared__ float Bs[BK][BN];
    __shared__ unsigned long long red[BM][16];
    const int tid = threadIdx.x;
    const int m0 = blockIdx.y * BM, n0 = blockIdx.x * BN;
    const int tx = tid & 15, ty = tid >> 4;
    const int lrow = tid >> 2, lk = (tid & 3) << 2;
    float acc[4][4] = {};
    for (int k0 = 0; k0 < HIDDEN; k0 += BK) {
        float4 a = *(const float4*)&h[(size_t)(m0 + lrow) * HIDDEN + k0 + lk];
        float4 b = *(const float4*)&outW[(size_t)(n0 + lrow) * HIDDEN + k0 + lk];
        __syncthreads();
        As[lk+0][lrow] = a.x; As[lk+1][lrow] = a.y; As[lk+2][lrow] = a.z; As[lk+3][lrow] = a.w;
        Bs[lk+0][lrow] = b.x; Bs[lk+1][lrow] = b.y; Bs[lk+2][lrow] = b.z; Bs[lk+3][lrow] = b.w;
        __syncthreads();
#pragma unroll
        for (int kk = 0; kk < BK; ++kk) {
            float4 av = *(const float4*)&As[kk][ty * 4];
            float4 bv = *(const float4*)&Bs[kk][tx * 4];
            float ar[4] = {av.x, av.y, av.z, av.w};
            float br[4] = {bv.x, bv.y, bv.z, bv.w};
#pragma unroll
            for (int i = 0; i < 4; ++i)
#pragma unroll
                for (int j = 0; j < 4; ++j) acc[i][j] += ar[i] * br[j];
        }
    }
#pragma unroll
    for (int i = 0; i < 4; ++i) {
        int r = m0 + ty * 4 + i;
        unsigned long long best = 0ULL;
#pragma unroll
        for (int j = 0; j < 4; ++j) {
            int c = n0 + tx * 4 + j;
            float v = acc[i][j] + outb[c] + gum_t[(size_t)r * VOCAB + c];
            unsigned long long key = pack_key(v, c);
            if (key > best) best = key;
        }
        red[ty * 4 + i][tx] = best;
    }
    __syncthreads();
    if (tid < BM) {
        unsigned long long best = red[tid][0];
#pragma unroll
        for (int q = 1; q < 16; ++q)
            if (red[tid][q] > best) best = red[tid][q];
        atomicMax(&keys_t[m0 + tid], best);
    }
}

// ---------------- finalize: tokens -> lengths -> scatter one-hots + length + eos_loss
__global__ __launch_bounds__(256) void k_final(const unsigned long long* __restrict__ keys,
                                               float* __restrict__ out) {
    int b = blockIdx.x * 256 + threadIdx.x;
    if (b >= BATCH) return;
    int toks[TSTEPS];
    int len = 1;
    bool done = false;
#pragma unroll
    for (int t = 0; t < TSTEPS; ++t) {
        int tok = (VOCAB - 1) - (int)(uint32_t)(keys[(size_t)t * BATCH + b] & 0xffffffffULL);
        toks[t] = tok;
        if (!done) len++;
        if (tok == EOS) done = true;
    }
    if (!done) len++;
    float* lang = out + (size_t)b * MAXLEN * VOCAB;
    lang[SOS] = 1.0f;  // position 0 = SOS one-hot, always inside mask (len >= 2)
#pragma unroll
    for (int t = 0; t < TSTEPS; ++t) {
        int pos = t + 1;
        if (pos < len) lang[(size_t)pos * VOCAB + toks[t]] = 1.0f;
    }
    if (len == MAXLEN) lang[(size_t)(MAXLEN - 1) * VOCAB + EOS] = 1.0f;
    out[(size_t)BATCH * MAXLEN * VOCAB + b] = (float)len;
    if (b == 0) out[(size_t)BATCH * MAXLEN * VOCAB + BATCH] = 0.0f;  // eos_loss
}

extern "C" void kernel_launch(void* const* d_in, const int* in_sizes, int n_in,
                              void* d_out, int out_size, void* d_ws, size_t ws_size,
                              hipStream_t stream) {
    const float* feats = (const float*)d_in[0];
    const int*   targets = (const int*)d_in[1];
    const float* featW = (const float*)d_in[2];
    const float* featb = (const float*)d_in[3];
    const float* embW  = (const float*)d_in[4];
    const float* initW = (const float*)d_in[5];
    const float* initb = (const float*)d_in[6];
    const float* Wih   = (const float*)d_in[7];
    const float* Whh   = (const float*)d_in[8];
    const float* bih   = (const float*)d_in[9];
    const float* bhh   = (const float*)d_in[10];
    const float* outW  = (const float*)d_in[11];
    const float* outb  = (const float*)d_in[12];
    const float* gumbel = (const float*)d_in[13];
    float* out = (float*)d_out;

    char* ws = (char*)d_ws;
    float* h  = (float*)(ws);                                   // 1 MB
    float* G  = (float*)(ws + (1 << 20));                       // 6 MB
    float* fe = (float*)(ws + 7 * (1 << 20));                   // 3 MB
    unsigned long long* keys = (unsigned long long*)(ws + 10 * (1 << 20));  // 152 KB

    hipMemsetAsync(d_out, 0, (size_t)out_size * sizeof(float), stream);
    hipMemsetAsync(keys, 0, (size_t)TSTEPS * BATCH * sizeof(unsigned long long), stream);

    k_fe<<<dim3(FEATSZ / BN, (BATCH * NOBJ) / BM), 256, 0, stream>>>(feats, featW, featb, fe);
    k_h0<<<dim3(HIDDEN / BN, BATCH / BM), 256, 0, stream>>>(fe, initW, initb, targets, h);

    for (int t = 0; t < TSTEPS; ++t) {
        const unsigned long long* kprev = (t == 0) ? nullptr : (keys + (size_t)(t - 1) * BATCH);
        k_gates<<<dim3((6 * HIDDEN) / BN, BATCH / BM), 256, 0, stream>>>(
            embW, h, Wih, Whh, bih, bhh, kprev, G);
        k_gru<<<dim3((BATCH * HIDDEN) / 256), 256, 0, stream>>>(G, h);
        k_logits<<<dim3(VOCAB / BN, BATCH / BM), 256, 0, stream>>>(
            h, outW, outb, gumbel + (size_t)t * BATCH * VOCAB, keys + (size_t)t * BATCH);
    }
    k_final<<<dim3(2), 256, 0, stream>>>(keys, out);
}